// Round 9
// baseline (91.429 us; speedup 1.0000x reference)
//
#include <hip/hip_runtime.h>
#include <hip/hip_bf16.h>

typedef __bf16 bf16_t;
typedef __bf16 bf16x8 __attribute__((ext_vector_type(8)));
typedef __bf16 bf16x4 __attribute__((ext_vector_type(4)));
typedef float  f32x4  __attribute__((ext_vector_type(4)));

#define B_   2
#define S_   2048
#define D_   1024
#define H_   16
#define HD_  64
#define HW   32
#define SCALE_ 0.125f

__device__ __forceinline__ void gl_lds16(const bf16_t* g, bf16_t* l) {
  __builtin_amdgcn_global_load_lds(
      (const __attribute__((address_space(1))) void*)g,
      (__attribute__((address_space(3))) void*)l, 16, 0, 0);
}

// ------------- fused converts: x fp32->bf16 (blocks 0..2047), W transpose (2048..3071)
__global__ __launch_bounds__(256) void k_conv(const float* __restrict__ X,
                                              const float* __restrict__ W0,
                                              const float* __restrict__ W1,
                                              const float* __restrict__ W2,
                                              const float* __restrict__ W3,
                                              bf16_t* __restrict__ Xb,
                                              bf16_t* __restrict__ Wt) {
  __shared__ bf16_t t[64][72];
  int bid = blockIdx.x;
  int tid = threadIdx.x;
  if (bid < 2048) {
    int i = bid * 256 + tid;
    const float4 a = ((const float4*)X)[i * 2];
    const float4 b = ((const float4*)X)[i * 2 + 1];
    bf16x8 r;
    r[0] = (bf16_t)a.x; r[1] = (bf16_t)a.y; r[2] = (bf16_t)a.z; r[3] = (bf16_t)a.w;
    r[4] = (bf16_t)b.x; r[5] = (bf16_t)b.y; r[6] = (bf16_t)b.z; r[7] = (bf16_t)b.w;
    ((bf16x8*)Xb)[i] = r;
    return;
  }
  int wb = bid - 2048;
  int wsel = wb >> 8;
  const float* W = (wsel == 0) ? W0 : (wsel == 1) ? W1 : (wsel == 2) ? W2 : W3;
  bf16_t* dst = Wt + (size_t)wsel * D_ * D_;
  int tile = wb & 255;
  int k0 = (tile >> 4) * 64, n0 = (tile & 15) * 64;
  int r = tid >> 4, c4 = (tid & 15) * 4;
#pragma unroll
  for (int i = 0; i < 4; ++i) {
    int row = i * 16 + r;
    float4 v = *(const float4*)(W + (size_t)(k0 + row) * D_ + n0 + c4);
    t[row][c4 + 0] = (bf16_t)v.x;
    t[row][c4 + 1] = (bf16_t)v.y;
    t[row][c4 + 2] = (bf16_t)v.z;
    t[row][c4 + 3] = (bf16_t)v.w;
  }
  __syncthreads();
#pragma unroll
  for (int i = 0; i < 4; ++i) {
    int row = i * 16 + r;
    bf16x4 o;
    o[0] = t[c4 + 0][row];
    o[1] = t[c4 + 1][row];
    o[2] = t[c4 + 2][row];
    o[3] = t[c4 + 3][row];
    *(bf16x4*)(dst + (size_t)(n0 + row) * D_ + k0 + c4) = o;
  }
}

// ---- QKV GEMM: round-6 2-barrier loop + XCD-chunked tile swizzle (T1) ----
// grid 768 = 8 XCDs x 96; each XCD owns an 8mt x 12nt rectangle:
// per-XCD L2 working set = 8 A-panels (2MB) + 12 B-panels (3MB) < 4MB.
__global__ __launch_bounds__(256) void k_gemm_qkv(const bf16_t* __restrict__ X,
                                                  const bf16_t* __restrict__ Wt,
                                                  bf16_t* __restrict__ Q,
                                                  bf16_t* __restrict__ K,
                                                  bf16_t* __restrict__ V) {
  __shared__ bf16_t sA[128 * 32];
  __shared__ bf16_t sB[128 * 32];
  int bid = blockIdx.x;
  int xcd = bid & 7, idx = bid >> 3;            // blockIdx%8 == XCD [m09]
  int mt = ((xcd & 3) << 3) + (idx & 7);        // 0..31
  int nt = (xcd >> 2) * 12 + (idx >> 3);        // 0..23
  int wsel = nt >> 3;
  int n0 = (nt & 7) * 128, m0 = mt * 128;
  const bf16_t* Wp = Wt + (size_t)wsel * D_ * D_;
  int tid = threadIdx.x, lane = tid & 63, wave = tid >> 6;
  int wr = (wave >> 1) * 64, wc = (wave & 1) * 64;
  int r0 = wave * 32 + (lane >> 2);
  int ce = (lane & 3) * 8;
  const bf16_t* gA0 = X + (size_t)(m0 + r0) * D_ + ce;
  const bf16_t* gB0 = Wp + (size_t)(n0 + r0) * D_ + ce;
  bf16_t* lA0 = sA + wave * 1024;
  bf16_t* lB0 = sB + wave * 1024;
  f32x4 acc[4][4] = {};
  int kq = (lane >> 4) * 8, rl = lane & 15;
  for (int kt = 0; kt < D_; kt += 32) {
    __syncthreads();
    gl_lds16(gA0 + kt, lA0);
    gl_lds16(gA0 + kt + (size_t)16 * D_, lA0 + 512);
    gl_lds16(gB0 + kt, lB0);
    gl_lds16(gB0 + kt + (size_t)16 * D_, lB0 + 512);
    __syncthreads();
    bf16x8 af[4], bfr[4];
#pragma unroll
    for (int m = 0; m < 4; ++m)
      af[m] = *(const bf16x8*)&sA[(wr + m * 16 + rl) * 32 + kq];
#pragma unroll
    for (int n = 0; n < 4; ++n)
      bfr[n] = *(const bf16x8*)&sB[(wc + n * 16 + rl) * 32 + kq];
#pragma unroll
    for (int m = 0; m < 4; ++m)
#pragma unroll
      for (int n = 0; n < 4; ++n)
        acc[m][n] = __builtin_amdgcn_mfma_f32_16x16x32_bf16(af[m], bfr[n], acc[m][n], 0, 0, 0);
  }
  float qscale = (wsel == 0) ? SCALE_ : 1.0f;
#pragma unroll
  for (int m = 0; m < 4; ++m) {
#pragma unroll
    for (int n = 0; n < 4; ++n) {
#pragma unroll
      for (int r = 0; r < 4; ++r) {
        int gm = m0 + wr + m * 16 + (lane >> 4) * 4 + r;
        int gn = n0 + wc + n * 16 + rl;
        int b = gm >> 11, s = gm & 2047;
        int h = gn >> 6, hd = gn & 63;
        bf16_t val = (bf16_t)(acc[m][n][r] * qscale);
        if (wsel == 0)
          Q[(((size_t)(b * H_ + h)) * S_ + s) * HD_ + hd] = val;
        else if (wsel == 1)
          K[(((size_t)(b * H_ + h)) * S_ + s) * HD_ + hd] = val;
        else
          V[(((size_t)(b * H_ + h)) * HD_ + hd) * S_ + s] = val;  // transposed
      }
    }
  }
}

// ---- out GEMM: round-6 loop + XCD swizzle (8 rects of 8mt x 4nt; 3MB/XCD) ----
__global__ __launch_bounds__(256) void k_gemm_out(const bf16_t* __restrict__ A,
                                                  const bf16_t* __restrict__ Wp,
                                                  const float* __restrict__ bo,
                                                  float* __restrict__ out) {
  __shared__ bf16_t sA[128 * 32];
  __shared__ bf16_t sB[128 * 32];
  int bid = blockIdx.x;
  int xcd = bid & 7, idx = bid >> 3;            // idx 0..31
  int mt = ((xcd & 3) << 3) + (idx & 7);        // 0..31
  int nt = ((xcd >> 2) << 2) + (idx >> 3);      // 0..7
  int n0 = nt * 128, m0 = mt * 128;
  int tid = threadIdx.x, lane = tid & 63, wave = tid >> 6;
  int wr = (wave >> 1) * 64, wc = (wave & 1) * 64;
  int r0 = wave * 32 + (lane >> 2);
  int ce = (lane & 3) * 8;
  const bf16_t* gA0 = A + (size_t)(m0 + r0) * D_ + ce;
  const bf16_t* gB0 = Wp + (size_t)(n0 + r0) * D_ + ce;
  bf16_t* lA0 = sA + wave * 1024;
  bf16_t* lB0 = sB + wave * 1024;
  f32x4 acc[4][4] = {};
  int kq = (lane >> 4) * 8, rl = lane & 15;
  for (int kt = 0; kt < D_; kt += 32) {
    __syncthreads();
    gl_lds16(gA0 + kt, lA0);
    gl_lds16(gA0 + kt + (size_t)16 * D_, lA0 + 512);
    gl_lds16(gB0 + kt, lB0);
    gl_lds16(gB0 + kt + (size_t)16 * D_, lB0 + 512);
    __syncthreads();
    bf16x8 af[4], bfr[4];
#pragma unroll
    for (int m = 0; m < 4; ++m)
      af[m] = *(const bf16x8*)&sA[(wr + m * 16 + rl) * 32 + kq];
#pragma unroll
    for (int n = 0; n < 4; ++n)
      bfr[n] = *(const bf16x8*)&sB[(wc + n * 16 + rl) * 32 + kq];
#pragma unroll
    for (int m = 0; m < 4; ++m)
#pragma unroll
      for (int n = 0; n < 4; ++n)
        acc[m][n] = __builtin_amdgcn_mfma_f32_16x16x32_bf16(af[m], bfr[n], acc[m][n], 0, 0, 0);
  }
#pragma unroll
  for (int m = 0; m < 4; ++m) {
#pragma unroll
    for (int n = 0; n < 4; ++n) {
#pragma unroll
      for (int r = 0; r < 4; ++r) {
        int gm = m0 + wr + m * 16 + (lane >> 4) * 4 + r;
        int gn = n0 + wc + n * 16 + rl;
        out[(size_t)gm * D_ + gn] = acc[m][n][r] + bo[gn];
      }
    }
  }
}

// ---------------- MFMA local causal attention (unchanged) ----------------
#define QB 64
#define KW 112
#define KLP 72
#define VTP 120

__global__ __launch_bounds__(256) void k_attn(const bf16_t* __restrict__ Q,
                                              const bf16_t* __restrict__ K,
                                              const bf16_t* __restrict__ Vt,
                                              bf16_t* __restrict__ O) {
  __shared__ bf16_t sK[KW][KLP];
  __shared__ bf16_t sV[HD_][VTP];
  __shared__ bf16_t sQ[QB][KLP];
  __shared__ bf16_t sP[4][16][KLP];
  int bid = blockIdx.x;
  int qb = bid & 31, bh = bid >> 5;
  int q0 = qb * QB;
  const bf16_t* Kp = K + (size_t)bh * S_ * HD_;
  const bf16_t* Vp = Vt + (size_t)bh * HD_ * S_;
  const bf16_t* Qp = Q + (size_t)bh * S_ * HD_;
  int tid = threadIdx.x;
  int wk0b = q0 - HW;
  for (int idx = tid; idx < KW * 8; idx += 256) {
    int row = idx >> 3, c8 = (idx & 7) * 8;
    int kg = wk0b + row;
    kg = kg < 0 ? 0 : (kg > S_ - 1 ? S_ - 1 : kg);
    *(bf16x8*)&sK[row][c8] = *(const bf16x8*)(Kp + (size_t)kg * HD_ + c8);
  }
  for (int idx = tid; idx < HD_ * 14; idx += 256) {
    int row = idx / 14, c8 = (idx % 14) * 8;
    int ks = wk0b + c8;
    ks = ks < 0 ? 0 : (ks > S_ - 8 ? S_ - 8 : ks);
    *(bf16x8*)&sV[row][c8] = *(const bf16x8*)(Vp + (size_t)row * S_ + ks);
  }
  for (int idx = tid; idx < QB * 8; idx += 256) {
    int row = idx >> 3, c8 = (idx & 7) * 8;
    *(bf16x8*)&sQ[row][c8] = *(const bf16x8*)(Qp + (size_t)(q0 + row) * HD_ + c8);
  }
  __syncthreads();
  int lane = tid & 63, wave = tid >> 6;
  int rl = lane & 15, hi = lane >> 4;
  int wko = wave * 16;
  f32x4 accs[4] = {};
#pragma unroll
  for (int ds = 0; ds < 2; ++ds) {
    bf16x8 qf = *(const bf16x8*)&sQ[wave * 16 + rl][ds * 32 + hi * 8];
#pragma unroll
    for (int kb = 0; kb < 4; ++kb) {
      bf16x8 kf = *(const bf16x8*)&sK[wko + kb * 16 + rl][ds * 32 + hi * 8];
      accs[kb] = __builtin_amdgcn_mfma_f32_16x16x32_bf16(kf, qf, accs[kb], 0, 0, 0);
    }
  }
  float p[4][4];
  float mx = -1e30f;
#pragma unroll
  for (int kb = 0; kb < 4; ++kb) {
#pragma unroll
    for (int r = 0; r < 4; ++r) {
      int kl = kb * 16 + hi * 4 + r;
      bool valid = (kl >= rl) && (kl <= rl + HW) && (wk0b + wko + kl >= 0);
      float s = valid ? accs[kb][r] : -1e30f;
      p[kb][r] = s;
      mx = fmaxf(mx, s);
    }
  }
  mx = fmaxf(mx, __shfl_xor(mx, 16));
  mx = fmaxf(mx, __shfl_xor(mx, 32));
  float sum = 0.f;
#pragma unroll
  for (int kb = 0; kb < 4; ++kb)
#pragma unroll
    for (int r = 0; r < 4; ++r) {
      p[kb][r] = __expf(p[kb][r] - mx);
      sum += p[kb][r];
    }
  sum += __shfl_xor(sum, 16);
  sum += __shfl_xor(sum, 32);
  float inv = 1.f / sum;
#pragma unroll
  for (int kb = 0; kb < 4; ++kb) {
    bf16x4 pv;
#pragma unroll
    for (int r = 0; r < 4; ++r) pv[r] = (bf16_t)(p[kb][r] * inv);
    *(bf16x4*)&sP[wave][rl][kb * 16 + hi * 4] = pv;
  }
  f32x4 acco[4] = {};
#pragma unroll
  for (int ks = 0; ks < 2; ++ks) {
    bf16x8 aP = *(const bf16x8*)&sP[wave][rl][ks * 32 + hi * 8];
#pragma unroll
    for (int n = 0; n < 4; ++n) {
      bf16x8 bV = *(const bf16x8*)&sV[n * 16 + rl][wko + ks * 32 + hi * 8];
      acco[n] = __builtin_amdgcn_mfma_f32_16x16x32_bf16(aP, bV, acco[n], 0, 0, 0);
    }
  }
  int b = bh >> 4, h = bh & 15;
#pragma unroll
  for (int n = 0; n < 4; ++n) {
#pragma unroll
    for (int r = 0; r < 4; ++r) {
      int qgl = q0 + wave * 16 + hi * 4 + r;
      int d = n * 16 + rl;
      O[((size_t)(b * S_ + qgl)) * D_ + h * HD_ + d] = (bf16_t)acco[n][r];
    }
  }
}

extern "C" void kernel_launch(void* const* d_in, const int* in_sizes, int n_in,
                              void* d_out, int out_size, void* d_ws, size_t ws_size,
                              hipStream_t stream) {
  const float* x  = (const float*)d_in[0];
  const float* Wq = (const float*)d_in[1];
  const float* Wk = (const float*)d_in[2];
  const float* Wv = (const float*)d_in[3];
  const float* Wo = (const float*)d_in[4];
  const float* bo = (const float*)d_in[5];
  float* out = (float*)d_out;
  char* ws = (char*)d_ws;
  bf16_t* xb = (bf16_t*)(ws);                       // 8 MB
  bf16_t* wt = (bf16_t*)(ws + (size_t)(8 << 20));   // 8 MB [4][1024][1024]
  bf16_t* qb = (bf16_t*)(ws + (size_t)(16 << 20));  // 8 MB [bh][s][64]
  bf16_t* kb = (bf16_t*)(ws + (size_t)(24 << 20));  // 8 MB [bh][s][64]
  bf16_t* vb = (bf16_t*)(ws + (size_t)(32 << 20));  // 8 MB [bh][64][s] (transposed)
  bf16_t* ob = (bf16_t*)(ws + (size_t)(40 << 20));  // 8 MB [b][s][1024]

  hipLaunchKernelGGL(k_conv, dim3(3072), dim3(256), 0, stream,
                     x, Wq, Wk, Wv, Wo, xb, wt);
  hipLaunchKernelGGL(k_gemm_qkv, dim3(768), dim3(256), 0, stream, xb, wt, qb, kb, vb);
  hipLaunchKernelGGL(k_attn, dim3(1024), dim3(256), 0, stream, qb, kb, vb, ob);
  hipLaunchKernelGGL(k_gemm_out, dim3(256), dim3(256), 0, stream,
                     ob, wt + (size_t)3 * D_ * D_, bo, out);
}

// Round 10
// 89.996 us; speedup vs baseline: 1.0159x; 1.0159x over previous
//
#include <hip/hip_runtime.h>
#include <hip/hip_bf16.h>

typedef __bf16 bf16_t;
typedef __bf16 bf16x8 __attribute__((ext_vector_type(8)));
typedef __bf16 bf16x4 __attribute__((ext_vector_type(4)));
typedef float  f32x4  __attribute__((ext_vector_type(4)));

#define B_   2
#define S_   2048
#define D_   1024
#define H_   16
#define HD_  64
#define HW   32
#define SCALE_ 0.125f

__device__ __forceinline__ void gl_lds16(const bf16_t* g, bf16_t* l) {
  __builtin_amdgcn_global_load_lds(
      (const __attribute__((address_space(1))) void*)g,
      (__attribute__((address_space(3))) void*)l, 16, 0, 0);
}

// ------------- fused converts: x fp32->bf16 (blocks 0..2047), W transpose (2048..3071)
__global__ __launch_bounds__(256) void k_conv(const float* __restrict__ X,
                                              const float* __restrict__ W0,
                                              const float* __restrict__ W1,
                                              const float* __restrict__ W2,
                                              const float* __restrict__ W3,
                                              bf16_t* __restrict__ Xb,
                                              bf16_t* __restrict__ Wt) {
  __shared__ bf16_t t[64][72];
  int bid = blockIdx.x;
  int tid = threadIdx.x;
  if (bid < 2048) {
    int i = bid * 256 + tid;
    const float4 a = ((const float4*)X)[i * 2];
    const float4 b = ((const float4*)X)[i * 2 + 1];
    bf16x8 r;
    r[0] = (bf16_t)a.x; r[1] = (bf16_t)a.y; r[2] = (bf16_t)a.z; r[3] = (bf16_t)a.w;
    r[4] = (bf16_t)b.x; r[5] = (bf16_t)b.y; r[6] = (bf16_t)b.z; r[7] = (bf16_t)b.w;
    ((bf16x8*)Xb)[i] = r;
    return;
  }
  int wb = bid - 2048;
  int wsel = wb >> 8;
  const float* W = (wsel == 0) ? W0 : (wsel == 1) ? W1 : (wsel == 2) ? W2 : W3;
  bf16_t* dst = Wt + (size_t)wsel * D_ * D_;
  int tile = wb & 255;
  int k0 = (tile >> 4) * 64, n0 = (tile & 15) * 64;
  int r = tid >> 4, c4 = (tid & 15) * 4;
#pragma unroll
  for (int i = 0; i < 4; ++i) {
    int row = i * 16 + r;
    float4 v = *(const float4*)(W + (size_t)(k0 + row) * D_ + n0 + c4);
    t[row][c4 + 0] = (bf16_t)v.x;
    t[row][c4 + 1] = (bf16_t)v.y;
    t[row][c4 + 2] = (bf16_t)v.z;
    t[row][c4 + 3] = (bf16_t)v.w;
  }
  __syncthreads();
#pragma unroll
  for (int i = 0; i < 4; ++i) {
    int row = i * 16 + r;
    bf16x4 o;
    o[0] = t[c4 + 0][row];
    o[1] = t[c4 + 1][row];
    o[2] = t[c4 + 2][row];
    o[3] = t[c4 + 3][row];
    *(bf16x4*)(dst + (size_t)(n0 + row) * D_ + k0 + c4) = o;
  }
}

// ---- QKV GEMM: 128x128, BK=64, 2-barrier loop, XOR-swizzled LDS (both-sides) ----
// LDS tile row = 64 elems (128B). Swizzle: LDS(row, c16) holds source col16
// c16 ^ (row&7).  Stage: lane l -> row l>>3, c16 l&7, src col16 (l&7)^(l>>3).
// Read frag (row, k-chunk s): c16 = s ^ (row&7).  16-lane subgroup -> 2-way (free).
__global__ __launch_bounds__(256) void k_gemm_qkv(const bf16_t* __restrict__ X,
                                                  const bf16_t* __restrict__ Wt,
                                                  bf16_t* __restrict__ Q,
                                                  bf16_t* __restrict__ K,
                                                  bf16_t* __restrict__ V) {
  __shared__ bf16_t sA[128 * 64];
  __shared__ bf16_t sB[128 * 64];
  int bid = blockIdx.x;
  int mt = bid & 31, nt = bid >> 5;           // round-6 mapping: XCD = mt%8 (3MB/XCD)
  int wsel = nt >> 3;
  int n0 = (nt & 7) * 128, m0 = mt * 128;
  const bf16_t* Wp = Wt + (size_t)wsel * D_ * D_;
  int tid = threadIdx.x, lane = tid & 63, wave = tid >> 6;
  int wr = (wave >> 1) * 64, wc = (wave & 1) * 64;
  // staging lane decomposition (8 rows per gl_lds round)
  int srow = lane >> 3;                        // 0..7
  int scol = ((lane & 7) ^ srow) * 8;          // pre-swizzled source col (elems)
  const bf16_t* gA0 = X + (size_t)(m0 + wave * 32 + srow) * D_ + scol;
  const bf16_t* gB0 = Wp + (size_t)(n0 + wave * 32 + srow) * D_ + scol;
  bf16_t* lA0 = sA + wave * 2048;              // 4 chunks x 512 elems
  bf16_t* lB0 = sB + wave * 2048;
  f32x4 acc[4][4] = {};
  int rl = lane & 15, hi = lane >> 4;
  int r7 = rl & 7;
  for (int kt = 0; kt < D_; kt += 64) {
    __syncthreads();                           // prev-iter LDS reads done
#pragma unroll
    for (int i = 0; i < 4; ++i) {              // 4 A-chunks + 4 B-chunks per wave
      gl_lds16(gA0 + kt + (size_t)(i * 8) * D_, lA0 + i * 512);
      gl_lds16(gB0 + kt + (size_t)(i * 8) * D_, lB0 + i * 512);
    }
    __syncthreads();                           // vmcnt(0) drain: tile ready
#pragma unroll
    for (int kk = 0; kk < 2; ++kk) {
      int cofs = (((kk * 4 + hi) ^ r7)) * 8;   // swizzled chunk offset (elems)
      bf16x8 af[4], bfr[4];
#pragma unroll
      for (int m = 0; m < 4; ++m)
        af[m] = *(const bf16x8*)&sA[(wr + m * 16 + rl) * 64 + cofs];
#pragma unroll
      for (int n = 0; n < 4; ++n)
        bfr[n] = *(const bf16x8*)&sB[(wc + n * 16 + rl) * 64 + cofs];
#pragma unroll
      for (int m = 0; m < 4; ++m)
#pragma unroll
        for (int n = 0; n < 4; ++n)
          acc[m][n] = __builtin_amdgcn_mfma_f32_16x16x32_bf16(af[m], bfr[n], acc[m][n], 0, 0, 0);
    }
  }
  float qscale = (wsel == 0) ? SCALE_ : 1.0f;
#pragma unroll
  for (int m = 0; m < 4; ++m) {
#pragma unroll
    for (int n = 0; n < 4; ++n) {
#pragma unroll
      for (int r = 0; r < 4; ++r) {
        int gm = m0 + wr + m * 16 + hi * 4 + r;
        int gn = n0 + wc + n * 16 + rl;
        int b = gm >> 11, s = gm & 2047;
        int h = gn >> 6, hd = gn & 63;
        bf16_t val = (bf16_t)(acc[m][n][r] * qscale);
        if (wsel == 0)
          Q[(((size_t)(b * H_ + h)) * S_ + s) * HD_ + hd] = val;
        else if (wsel == 1)
          K[(((size_t)(b * H_ + h)) * S_ + s) * HD_ + hd] = val;
        else
          V[(((size_t)(b * H_ + h)) * HD_ + hd) * S_ + s] = val;  // transposed
      }
    }
  }
}

// ---- out GEMM: same BK=64 swizzled structure, fp32 epilogue ----
__global__ __launch_bounds__(256) void k_gemm_out(const bf16_t* __restrict__ A,
                                                  const bf16_t* __restrict__ Wp,
                                                  const float* __restrict__ bo,
                                                  float* __restrict__ out) {
  __shared__ bf16_t sA[128 * 64];
  __shared__ bf16_t sB[128 * 64];
  int bid = blockIdx.x;
  int mt = bid & 31, nt = bid >> 5;
  int n0 = nt * 128, m0 = mt * 128;
  int tid = threadIdx.x, lane = tid & 63, wave = tid >> 6;
  int wr = (wave >> 1) * 64, wc = (wave & 1) * 64;
  int srow = lane >> 3;
  int scol = ((lane & 7) ^ srow) * 8;
  const bf16_t* gA0 = A + (size_t)(m0 + wave * 32 + srow) * D_ + scol;
  const bf16_t* gB0 = Wp + (size_t)(n0 + wave * 32 + srow) * D_ + scol;
  bf16_t* lA0 = sA + wave * 2048;
  bf16_t* lB0 = sB + wave * 2048;
  f32x4 acc[4][4] = {};
  int rl = lane & 15, hi = lane >> 4;
  int r7 = rl & 7;
  for (int kt = 0; kt < D_; kt += 64) {
    __syncthreads();
#pragma unroll
    for (int i = 0; i < 4; ++i) {
      gl_lds16(gA0 + kt + (size_t)(i * 8) * D_, lA0 + i * 512);
      gl_lds16(gB0 + kt + (size_t)(i * 8) * D_, lB0 + i * 512);
    }
    __syncthreads();
#pragma unroll
    for (int kk = 0; kk < 2; ++kk) {
      int cofs = (((kk * 4 + hi) ^ r7)) * 8;
      bf16x8 af[4], bfr[4];
#pragma unroll
      for (int m = 0; m < 4; ++m)
        af[m] = *(const bf16x8*)&sA[(wr + m * 16 + rl) * 64 + cofs];
#pragma unroll
      for (int n = 0; n < 4; ++n)
        bfr[n] = *(const bf16x8*)&sB[(wc + n * 16 + rl) * 64 + cofs];
#pragma unroll
      for (int m = 0; m < 4; ++m)
#pragma unroll
        for (int n = 0; n < 4; ++n)
          acc[m][n] = __builtin_amdgcn_mfma_f32_16x16x32_bf16(af[m], bfr[n], acc[m][n], 0, 0, 0);
    }
  }
#pragma unroll
  for (int m = 0; m < 4; ++m) {
#pragma unroll
    for (int n = 0; n < 4; ++n) {
#pragma unroll
      for (int r = 0; r < 4; ++r) {
        int gm = m0 + wr + m * 16 + hi * 4 + r;
        int gn = n0 + wc + n * 16 + rl;
        out[(size_t)gm * D_ + gn] = acc[m][n][r] + bo[gn];
      }
    }
  }
}

// ---------------- MFMA local causal attention (unchanged) ----------------
#define QB 64
#define KW 112
#define KLP 72
#define VTP 120

__global__ __launch_bounds__(256) void k_attn(const bf16_t* __restrict__ Q,
                                              const bf16_t* __restrict__ K,
                                              const bf16_t* __restrict__ Vt,
                                              bf16_t* __restrict__ O) {
  __shared__ bf16_t sK[KW][KLP];
  __shared__ bf16_t sV[HD_][VTP];
  __shared__ bf16_t sQ[QB][KLP];
  __shared__ bf16_t sP[4][16][KLP];
  int bid = blockIdx.x;
  int qb = bid & 31, bh = bid >> 5;
  int q0 = qb * QB;
  const bf16_t* Kp = K + (size_t)bh * S_ * HD_;
  const bf16_t* Vp = Vt + (size_t)bh * HD_ * S_;
  const bf16_t* Qp = Q + (size_t)bh * S_ * HD_;
  int tid = threadIdx.x;
  int wk0b = q0 - HW;
  for (int idx = tid; idx < KW * 8; idx += 256) {
    int row = idx >> 3, c8 = (idx & 7) * 8;
    int kg = wk0b + row;
    kg = kg < 0 ? 0 : (kg > S_ - 1 ? S_ - 1 : kg);
    *(bf16x8*)&sK[row][c8] = *(const bf16x8*)(Kp + (size_t)kg * HD_ + c8);
  }
  for (int idx = tid; idx < HD_ * 14; idx += 256) {
    int row = idx / 14, c8 = (idx % 14) * 8;
    int ks = wk0b + c8;
    ks = ks < 0 ? 0 : (ks > S_ - 8 ? S_ - 8 : ks);
    *(bf16x8*)&sV[row][c8] = *(const bf16x8*)(Vp + (size_t)row * S_ + ks);
  }
  for (int idx = tid; idx < QB * 8; idx += 256) {
    int row = idx >> 3, c8 = (idx & 7) * 8;
    *(bf16x8*)&sQ[row][c8] = *(const bf16x8*)(Qp + (size_t)(q0 + row) * HD_ + c8);
  }
  __syncthreads();
  int lane = tid & 63, wave = tid >> 6;
  int rl = lane & 15, hi = lane >> 4;
  int wko = wave * 16;
  f32x4 accs[4] = {};
#pragma unroll
  for (int ds = 0; ds < 2; ++ds) {
    bf16x8 qf = *(const bf16x8*)&sQ[wave * 16 + rl][ds * 32 + hi * 8];
#pragma unroll
    for (int kb = 0; kb < 4; ++kb) {
      bf16x8 kf = *(const bf16x8*)&sK[wko + kb * 16 + rl][ds * 32 + hi * 8];
      accs[kb] = __builtin_amdgcn_mfma_f32_16x16x32_bf16(kf, qf, accs[kb], 0, 0, 0);
    }
  }
  float p[4][4];
  float mx = -1e30f;
#pragma unroll
  for (int kb = 0; kb < 4; ++kb) {
#pragma unroll
    for (int r = 0; r < 4; ++r) {
      int kl = kb * 16 + hi * 4 + r;
      bool valid = (kl >= rl) && (kl <= rl + HW) && (wk0b + wko + kl >= 0);
      float s = valid ? accs[kb][r] : -1e30f;
      p[kb][r] = s;
      mx = fmaxf(mx, s);
    }
  }
  mx = fmaxf(mx, __shfl_xor(mx, 16));
  mx = fmaxf(mx, __shfl_xor(mx, 32));
  float sum = 0.f;
#pragma unroll
  for (int kb = 0; kb < 4; ++kb)
#pragma unroll
    for (int r = 0; r < 4; ++r) {
      p[kb][r] = __expf(p[kb][r] - mx);
      sum += p[kb][r];
    }
  sum += __shfl_xor(sum, 16);
  sum += __shfl_xor(sum, 32);
  float inv = 1.f / sum;
#pragma unroll
  for (int kb = 0; kb < 4; ++kb) {
    bf16x4 pv;
#pragma unroll
    for (int r = 0; r < 4; ++r) pv[r] = (bf16_t)(p[kb][r] * inv);
    *(bf16x4*)&sP[wave][rl][kb * 16 + hi * 4] = pv;
  }
  f32x4 acco[4] = {};
#pragma unroll
  for (int ks = 0; ks < 2; ++ks) {
    bf16x8 aP = *(const bf16x8*)&sP[wave][rl][ks * 32 + hi * 8];
#pragma unroll
    for (int n = 0; n < 4; ++n) {
      bf16x8 bV = *(const bf16x8*)&sV[n * 16 + rl][wko + ks * 32 + hi * 8];
      acco[n] = __builtin_amdgcn_mfma_f32_16x16x32_bf16(aP, bV, acco[n], 0, 0, 0);
    }
  }
  int b = bh >> 4, h = bh & 15;
#pragma unroll
  for (int n = 0; n < 4; ++n) {
#pragma unroll
    for (int r = 0; r < 4; ++r) {
      int qgl = q0 + wave * 16 + hi * 4 + r;
      int d = n * 16 + rl;
      O[((size_t)(b * S_ + qgl)) * D_ + h * HD_ + d] = (bf16_t)acco[n][r];
    }
  }
}

extern "C" void kernel_launch(void* const* d_in, const int* in_sizes, int n_in,
                              void* d_out, int out_size, void* d_ws, size_t ws_size,
                              hipStream_t stream) {
  const float* x  = (const float*)d_in[0];
  const float* Wq = (const float*)d_in[1];
  const float* Wk = (const float*)d_in[2];
  const float* Wv = (const float*)d_in[3];
  const float* Wo = (const float*)d_in[4];
  const float* bo = (const float*)d_in[5];
  float* out = (float*)d_out;
  char* ws = (char*)d_ws;
  bf16_t* xb = (bf16_t*)(ws);                       // 8 MB
  bf16_t* wt = (bf16_t*)(ws + (size_t)(8 << 20));   // 8 MB [4][1024][1024]
  bf16_t* qb = (bf16_t*)(ws + (size_t)(16 << 20));  // 8 MB [bh][s][64]
  bf16_t* kb = (bf16_t*)(ws + (size_t)(24 << 20));  // 8 MB [bh][s][64]
  bf16_t* vb = (bf16_t*)(ws + (size_t)(32 << 20));  // 8 MB [bh][64][s] (transposed)
  bf16_t* ob = (bf16_t*)(ws + (size_t)(40 << 20));  // 8 MB [b][s][1024]

  hipLaunchKernelGGL(k_conv, dim3(3072), dim3(256), 0, stream,
                     x, Wq, Wk, Wv, Wo, xb, wt);
  hipLaunchKernelGGL(k_gemm_qkv, dim3(768), dim3(256), 0, stream, xb, wt, qb, kb, vb);
  hipLaunchKernelGGL(k_attn, dim3(1024), dim3(256), 0, stream, qb, kb, vb, ob);
  hipLaunchKernelGGL(k_gemm_out, dim3(256), dim3(256), 0, stream,
                     ob, wt + (size_t)3 * D_ * D_, bo, out);
}